// Round 10
// baseline (193.765 us; speedup 1.0000x reference)
//
#include <hip/hip_runtime.h>
#include <math.h>

#define HEADS 2
#define C1    33
#define C2    550
#define D1    66     // HEADS*C1
#define D2    1100   // HEADS*C2
#define IN1   256
#define PROJW 288    // padded q|k|v|s width (264 -> 288 = 3*96)
#define KU    224    // padded U width (198 -> 224 = 7*32)
#define N2P   1152   // padded final cols (1100 -> 1152 = 12*96)
#define KZ    96     // padded K for z-GEMM (66 -> 96)
#define ZW    144    // Z row stride (136 used -> 144)

typedef __attribute__((ext_vector_type(8))) short bfrag;   // 8 bf16 (bits in short)
typedef __attribute__((ext_vector_type(4))) float f32x4;

__device__ inline unsigned short f2bf(float f) {
    unsigned int u = __float_as_uint(f);
    u += 0x7FFFu + ((u >> 16) & 1u);
    return (unsigned short)(u >> 16);
}

// XCD-aware swizzle: blocks with equal bid%8 (same XCD) get contiguous work
// slots, so all col-groups of a row-tile run on one XCD and share its L2.
__device__ inline int xcd_slot(int bid, int slots) {
    return (bid >> 3) + (bid & 7) * slots;
}

// ---------------- fp32 -> bf16 conversion of x ----------------
__global__ void k_cvt(const float* __restrict__ x, unsigned short* __restrict__ xb, int total4) {
    int i = blockIdx.x * blockDim.x + threadIdx.x;
    if (i >= total4) return;
    float4 v = ((const float4*)x)[i];
    ushort4 o;
    o.x = f2bf(v.x); o.y = f2bf(v.y); o.z = f2bf(v.z); o.w = f2bf(v.w);
    ((ushort4*)xb)[i] = o;
}

// ---------------- Wt1 fragment-order [3][8][4][96][8] + bcat[288] ----------------
__global__ void k_prep1(const float* __restrict__ Wq, const float* __restrict__ bq,
                        const float* __restrict__ Wk, const float* __restrict__ bk,
                        const float* __restrict__ Wv, const float* __restrict__ bv,
                        const float* __restrict__ Ws, const float* __restrict__ bs,
                        unsigned short* __restrict__ Wt1, float* __restrict__ bcat) {
    int bid = blockIdx.x;            // (g*8+ks)*4+lk, 96 blocks
    int lk = bid & 3, t = bid >> 2;
    int ks = t & 7, g = t >> 3;
    int col = threadIdx.x;           // 0..95
    int c = g * 96 + col;
    int k0 = ks * 32 + lk * 8;
    short vals[8];
    float bia = 0.f;
    if (c < 4 * D1) {
        int m = c / D1, j = c % D1;
        const float* W; const float* B;
        switch (m) {
            case 0: W = Wq; B = bq; break;
            case 1: W = Wk; B = bk; break;
            case 2: W = Wv; B = bv; break;
            default: W = Ws; B = bs; break;
        }
        #pragma unroll
        for (int e = 0; e < 8; e++) vals[e] = (short)f2bf(W[(size_t)(k0 + e) * D1 + j]);
        bia = B[j];
    } else {
        #pragma unroll
        for (int e = 0; e < 8; e++) vals[e] = 0;
    }
    *(bfrag*)&Wt1[((size_t)bid * 96 + col) * 8] = *(bfrag*)vals;
    if (ks == 0 && lk == 0) bcat[c] = bia;
}

// ---------------- W2t fragment-order [12][7][4][96][8] ----------------
// rows 198/199 = head-masked bv2 (flag columns); row 223 = bs2 (const-1 column).
__global__ void k_prep2(const float* __restrict__ Wv2, const float* __restrict__ bv2,
                        const float* __restrict__ Ws2, const float* __restrict__ bs2,
                        unsigned short* __restrict__ W2t) {
    int bid = blockIdx.x;            // (g*7+ks)*4+lk, 336 blocks
    int lk = bid & 3, t = bid >> 2;
    int ks = t % 7, g = t / 7;
    int col = threadIdx.x;           // 0..95
    int c = g * 96 + col;
    int k0 = ks * 32 + lk * 8;
    short vals[8];
    #pragma unroll
    for (int e = 0; e < 8; e++) {
        int k = k0 + e;
        float val = 0.f;
        if (c < D2) {
            if (c < C2) {
                if (k < 66) val = Wv2[(size_t)k * D2 + c];
                else if (k >= 132 && k < 198) val = Ws2[(size_t)(k - 132) * D2 + c];
                else if (k == 198) val = bv2[c];
                else if (k == 223) val = bs2[c];
            } else {
                if (k >= 66 && k < 132) val = Wv2[(size_t)(k - 66) * D2 + c];
                else if (k >= 132 && k < 198) val = Ws2[(size_t)(k - 132) * D2 + c];
                else if (k == 199) val = bv2[c];
                else if (k == 223) val = bs2[c];
            }
        }
        vals[e] = (short)f2bf(val);
    }
    *(bfrag*)&W2t[((size_t)bid * 96 + col) * 8] = *(bfrag*)vals;
}

// ---------------- CSR construction ----------------
__global__ void k_hist(const int* __restrict__ dst, int E, int* __restrict__ cnt) {
    int e = blockIdx.x * blockDim.x + threadIdx.x;
    if (e < E) atomicAdd(&cnt[dst[e]], 1);
}

__global__ void k_scan(const int* __restrict__ cnt, int* __restrict__ roff,
                       int* __restrict__ pos, int N) {
    __shared__ int wsum[16];
    __shared__ int carry_s;
    int tid = threadIdx.x, wid = tid >> 6, lane = tid & 63;
    if (tid == 0) { carry_s = 0; roff[0] = 0; }
    __syncthreads();
    for (int base = 0; base < N; base += 1024) {
        int i = base + tid;
        int v = (i < N) ? cnt[i] : 0;
        int x = v;
        #pragma unroll
        for (int s = 1; s < 64; s <<= 1) {
            int t = __shfl_up(x, s, 64);
            if (lane >= s) x += t;
        }
        if (lane == 63) wsum[wid] = x;
        __syncthreads();
        if (tid < 16) {
            int y = wsum[tid];
            #pragma unroll
            for (int s = 1; s < 16; s <<= 1) {
                int t = __shfl_up(y, s, 16);
                if (tid >= s) y += t;
            }
            wsum[tid] = y;
        }
        __syncthreads();
        int carry = carry_s;
        int incl = carry + (wid ? wsum[wid - 1] : 0) + x;
        if (i < N) { roff[i + 1] = incl; pos[i] = incl - v; }
        __syncthreads();
        if (tid == 0) carry_s = carry + wsum[15];
        __syncthreads();
    }
}

__global__ void k_fill(const int* __restrict__ src, const int* __restrict__ dst, int E,
                       int* __restrict__ pos, int* __restrict__ elist) {
    int e = blockIdx.x * blockDim.x + threadIdx.x;
    if (e < E) {
        int slot = atomicAdd(&pos[dst[e]], 1);
        elist[slot] = src[e];
    }
}

// ---------------- MFMA GEMM 1: proj[N][288] = x_bf16 @ W^T + bcat ----------------
__global__ __launch_bounds__(256) void k_mm1(
        const unsigned short* __restrict__ A, const unsigned short* __restrict__ B,
        const float* __restrict__ bias, float* __restrict__ proj, int N,
        int nRow, int slots) {
    int s = xcd_slot(blockIdx.x, slots);
    if (s >= nRow * 3) return;
    int rowt = s / 3, g = s - rowt * 3;
    int cbase = g * 96;
    int wave = threadIdx.x >> 6, lane = threadIdx.x & 63;
    int lr = lane & 15, lk = lane >> 4;
    int rbase = rowt * 128 + wave * 32;
    int ar[2];
    #pragma unroll
    for (int mi = 0; mi < 2; mi++) {
        int r = rbase + mi * 16 + lr;
        ar[mi] = (r < N) ? r : (N - 1);
    }
    bfrag a[2][8];
    #pragma unroll
    for (int mi = 0; mi < 2; mi++)
        #pragma unroll
        for (int ks = 0; ks < 8; ks++)
            a[mi][ks] = *(const bfrag*)(A + (size_t)ar[mi] * IN1 + ks * 32 + lk * 8);
    f32x4 acc[2][6];
    #pragma unroll
    for (int mi = 0; mi < 2; mi++)
        #pragma unroll
        for (int ni = 0; ni < 6; ni++) acc[mi][ni] = (f32x4){0.f, 0.f, 0.f, 0.f};
    #pragma unroll
    for (int ks = 0; ks < 8; ks++) {
        bfrag b[6];
        #pragma unroll
        for (int ni = 0; ni < 6; ni++)
            b[ni] = *(const bfrag*)(B + (size_t)(g * 8 + ks) * 3072 + lk * 768 + (ni * 16 + lr) * 8);
        #pragma unroll
        for (int mi = 0; mi < 2; mi++)
            #pragma unroll
            for (int ni = 0; ni < 6; ni++)
                acc[mi][ni] = __builtin_amdgcn_mfma_f32_16x16x32_bf16(a[mi][ks], b[ni], acc[mi][ni], 0, 0, 0);
    }
    #pragma unroll
    for (int mi = 0; mi < 2; mi++) {
        #pragma unroll
        for (int ni = 0; ni < 6; ni++) {
            int col = cbase + ni * 16 + lr;
            float bia = bias[col];
            #pragma unroll
            for (int r = 0; r < 4; r++) {
                int row = rbase + mi * 16 + lk * 4 + r;
                if (row < N) proj[(size_t)row * PROJW + col] = acc[mi][ni][r] + bia;
            }
        }
    }
}

// ---------------- conv1 edge phase: 4 waves = (head, half), split + merge ----------------
__global__ __launch_bounds__(256) void k_conv1(
        const float* __restrict__ proj, const int* __restrict__ roff,
        const int* __restrict__ elist, float* __restrict__ h1,
        unsigned short* __restrict__ h1b, int N) {
    __shared__ float sm_m[4], sm_l[4], sm_acc[2][C1];
    int n = blockIdx.x;
    int wid = threadIdx.x >> 6;
    int lane = threadIdx.x & 63;
    int h = wid >> 1, half = wid & 1;
    size_t pb = (size_t)n * PROJW;
    int hc = h * C1;
    bool ok = (lane < C1);
    float my_q = ok ? proj[pb + hc + lane] : 0.f;
    int E0 = roff[n], E1 = roff[n + 1];
    int hd2 = (E1 - E0 + 1) >> 1;
    int e  = E0 + (half ? hd2 : 0);
    int e1 = half ? E1 : (E0 + hd2);
    float m = -INFINITY, lsum = 0.f, acc = 0.f;
    const float isc = 0.17407765595569785f;  // 1/sqrt(33)
    for (; e + 3 < e1; e += 4) {
        int s0 = elist[e], s1 = elist[e + 1], s2 = elist[e + 2], s3 = elist[e + 3];
        size_t b0 = (size_t)s0 * PROJW, b1 = (size_t)s1 * PROJW;
        size_t b2 = (size_t)s2 * PROJW, b3 = (size_t)s3 * PROJW;
        float k0 = ok ? proj[b0 + 66 + hc + lane] : 0.f;
        float k1 = ok ? proj[b1 + 66 + hc + lane] : 0.f;
        float k2 = ok ? proj[b2 + 66 + hc + lane] : 0.f;
        float k3 = ok ? proj[b3 + 66 + hc + lane] : 0.f;
        float v0 = ok ? proj[b0 + 132 + hc + lane] : 0.f;
        float v1 = ok ? proj[b1 + 132 + hc + lane] : 0.f;
        float v2 = ok ? proj[b2 + 132 + hc + lane] : 0.f;
        float v3 = ok ? proj[b3 + 132 + hc + lane] : 0.f;
        float p0 = my_q * k0, p1 = my_q * k1, p2 = my_q * k2, p3 = my_q * k3;
        #pragma unroll
        for (int off = 32; off >= 1; off >>= 1) {
            p0 += __shfl_xor(p0, off, 64);
            p1 += __shfl_xor(p1, off, 64);
            p2 += __shfl_xor(p2, off, 64);
            p3 += __shfl_xor(p3, off, 64);
        }
        float a0 = p0 * isc, a1 = p1 * isc, a2 = p2 * isc, a3 = p3 * isc;
        float mp = fmaxf(fmaxf(a0, a1), fmaxf(a2, a3));
        float e0v = __expf(a0 - mp), e1v = __expf(a1 - mp);
        float e2v = __expf(a2 - mp), e3v = __expf(a3 - mp);
        float lp = (e0v + e1v) + (e2v + e3v);
        float ap = (e0v * v0 + e1v * v1) + (e2v * v2 + e3v * v3);
        float mnew = fmaxf(m, mp);
        float sc = __expf(m - mnew), sp = __expf(mp - mnew);
        lsum = lsum * sc + lp * sp;
        acc  = acc * sc + ap * sp;
        m = mnew;
    }
    for (; e + 1 < e1; e += 2) {
        int sa = elist[e], sb = elist[e + 1];
        size_t ba = (size_t)sa * PROJW, bb = (size_t)sb * PROJW;
        float ka = ok ? proj[ba + 66 + hc + lane] : 0.f;
        float va = ok ? proj[ba + 132 + hc + lane] : 0.f;
        float kb = ok ? proj[bb + 66 + hc + lane] : 0.f;
        float vb = ok ? proj[bb + 132 + hc + lane] : 0.f;
        float pa = my_q * ka, pbv = my_q * kb;
        #pragma unroll
        for (int off = 32; off >= 1; off >>= 1) {
            pa  += __shfl_xor(pa, off, 64);
            pbv += __shfl_xor(pbv, off, 64);
        }
        float aa = pa * isc, ab = pbv * isc;
        float mp = fmaxf(aa, ab);
        float ea = __expf(aa - mp), eb = __expf(ab - mp);
        float lp = ea + eb, ap = ea * va + eb * vb;
        float mnew = fmaxf(m, mp);
        float sc = __expf(m - mnew), sp = __expf(mp - mnew);
        lsum = lsum * sc + lp * sp;
        acc  = acc * sc + ap * sp;
        m = mnew;
    }
    if (e < e1) {
        int s = elist[e];
        size_t sb = (size_t)s * PROJW;
        float kv = ok ? proj[sb + 66 + hc + lane] : 0.f;
        float vv = ok ? proj[sb + 132 + hc + lane] : 0.f;
        float prod = my_q * kv;
        #pragma unroll
        for (int off = 32; off >= 1; off >>= 1) prod += __shfl_xor(prod, off, 64);
        float alpha = prod * isc;
        float mnew = fmaxf(m, alpha);
        float sc = __expf(m - mnew);
        float p = __expf(alpha - mnew);
        lsum = lsum * sc + p;
        acc  = acc * sc + p * vv;
        m = mnew;
    }
    if (half) {
        sm_m[wid] = m; sm_l[wid] = lsum;
        if (ok) sm_acc[h][lane] = acc;
    }
    __syncthreads();
    if (!half) {
        float mB = sm_m[wid + 1], lB = sm_l[wid + 1];
        float accB = ok ? sm_acc[h][lane] : 0.f;
        float mnew = fmaxf(m, mB);
        float sA = (m > -INFINITY) ? __expf(m - mnew) : 0.f;
        float sB = (mB > -INFINITY) ? __expf(mB - mnew) : 0.f;
        lsum = lsum * sA + lB * sB;
        acc  = acc * sA + accB * sB;
        if (ok) {
            float s1v = proj[pb + 198 + hc + lane];
            float res = (lsum > 0.f) ? acc / lsum : 0.f;
            float val = res + s1v;
            h1[(size_t)n * D1 + hc + lane] = val;
            h1b[(size_t)n * KZ + hc + lane] = f2bf(val);
        } else if (h == 1 && lane >= C1 && lane < C1 + 30) {
            h1b[(size_t)n * KZ + D1 + (lane - C1)] = 0;  // zero pad cols 66..95
        }
    }
}

// ---------------- precompute G = Wq2_h Wk2_h^T + bias dots: one wave per dot ----------------
__global__ __launch_bounds__(256) void k_precomp(
        const float* __restrict__ Wq2, const float* __restrict__ bq2,
        const float* __restrict__ Wk2, const float* __restrict__ bk2,
        float* __restrict__ G, float* __restrict__ wqbk,
        float* __restrict__ wkbq, float* __restrict__ cc) {
    int wave = threadIdx.x >> 6, lane = threadIdx.x & 63;
    int j = blockIdx.x * 4 + wave;
    if (j >= 8978) return;
    const float *u, *v;
    float* outp;
    if (j < 8976) {
        int h = j / 4488;
        int r = j % 4488;
        int a = r / 68, b = r % 68;
        if (b < 66)      { u = Wq2 + (size_t)a * D2 + h * C2; v = Wk2 + (size_t)b * D2 + h * C2; outp = &G[h * 4356 + a * 66 + b]; }
        else if (b == 66){ u = Wq2 + (size_t)a * D2 + h * C2; v = bk2 + h * C2;                  outp = &wqbk[h * 66 + a]; }
        else             { u = Wk2 + (size_t)a * D2 + h * C2; v = bq2 + h * C2;                  outp = &wkbq[h * 66 + a]; }
    } else {
        int h = j - 8976;
        u = bq2 + h * C2; v = bk2 + h * C2; outp = &cc[h];
    }
    float acc = 0.f;
    for (int c = lane; c < C2; c += 64) acc += u[c] * v[c];
    #pragma unroll
    for (int off = 32; off >= 1; off >>= 1) acc += __shfl_xor(acc, off, 64);
    if (lane == 0) *outp = acc;
}

// ---------------- GBt fragment-order [2][3][4][96][8] ----------------
__global__ void k_prepz(const float* __restrict__ G, const float* __restrict__ wqbk,
                        const float* __restrict__ wkbq, unsigned short* __restrict__ GBt) {
    int bid = blockIdx.x;            // (g*3+ks)*4+lk, 24 blocks
    int lk = bid & 3, t = bid >> 2;
    int ks = t % 3, g = t / 3;
    int col = threadIdx.x;           // 0..95
    int r = g * 96 + col;
    int k0 = ks * 32 + lk * 8;
    short vals[8];
    #pragma unroll
    for (int e = 0; e < 8; e++) {
        int k = k0 + e;
        float v = 0.f;
        if (k < D1) {
            if (r < 132) v = G[r * D1 + k];
            else if (r < 134) v = wqbk[(r - 132) * D1 + k];
            else if (r < 136) v = wkbq[(r - 134) * D1 + k];
        }
        vals[e] = (short)f2bf(v);
    }
    *(bfrag*)&GBt[((size_t)bid * 96 + col) * 8] = *(bfrag*)vals;
}

// ---------------- MFMA GEMM z: Z[N][144] = h1b[N][96] @ GBt^T (cols 0..135 valid) ----------------
__global__ __launch_bounds__(256) void k_mmz(
        const unsigned short* __restrict__ A, const unsigned short* __restrict__ B,
        float* __restrict__ Z, int N, int nRow, int slots) {
    int s = xcd_slot(blockIdx.x, slots);
    if (s >= nRow * 2) return;
    int rowt = s >> 1, g = s & 1;
    int wave = threadIdx.x >> 6, lane = threadIdx.x & 63;
    int lr = lane & 15, lk = lane >> 4;
    int rbase = rowt * 64 + (wave >> 1) * 32;
    int ch = (wave & 1) * 48;
    int cbase = g * 96 + ch;
    f32x4 acc[2][3];
    #pragma unroll
    for (int i = 0; i < 2; i++)
        #pragma unroll
        for (int j = 0; j < 3; j++) acc[i][j] = (f32x4){0.f, 0.f, 0.f, 0.f};
    int ar[2];
    #pragma unroll
    for (int mi = 0; mi < 2; mi++) {
        int r = rbase + mi * 16 + lr;
        ar[mi] = (r < N) ? r : (N - 1);
    }
    #pragma unroll
    for (int ks = 0; ks < 3; ks++) {
        bfrag a[2], b[3];
        #pragma unroll
        for (int mi = 0; mi < 2; mi++)
            a[mi] = *(const bfrag*)(A + (size_t)ar[mi] * KZ + ks * 32 + lk * 8);
        #pragma unroll
        for (int ni = 0; ni < 3; ni++)
            b[ni] = *(const bfrag*)(B + (size_t)(g * 3 + ks) * 3072 + lk * 768 + (ch + ni * 16 + lr) * 8);
        #pragma unroll
        for (int mi = 0; mi < 2; mi++)
            #pragma unroll
            for (int ni = 0; ni < 3; ni++)
                acc[mi][ni] = __builtin_amdgcn_mfma_f32_16x16x32_bf16(a[mi], b[ni], acc[mi][ni], 0, 0, 0);
    }
    #pragma unroll
    for (int mi = 0; mi < 2; mi++) {
        #pragma unroll
        for (int ni = 0; ni < 3; ni++) {
            int col = cbase + ni * 16 + lr;
            if (col >= 136) continue;
            #pragma unroll
            for (int r = 0; r < 4; r++) {
                int row = rbase + mi * 16 + lk * 4 + r;
                if (row < N) Z[(size_t)row * ZW + col] = acc[mi][ni][r];
            }
        }
    }
}

// ---------------- conv2 edge phase: 4 waves = (head, half), split + merge ----------------
__global__ __launch_bounds__(256) void k_conv2(
        const float* __restrict__ h1, const float* __restrict__ Z,
        const float* __restrict__ cc, const int* __restrict__ roff,
        const int* __restrict__ elist, unsigned short* __restrict__ U, int N) {
    __shared__ float sm_m[4], sm_l[4], sm_a0[2][64], sm_a1[2][2];
    int n = blockIdx.x;
    int wid = threadIdx.x >> 6;
    int lane = threadIdx.x & 63;
    int h = wid >> 1, half = wid & 1;
    int c0 = lane, c1 = lane + 64;
    bool ok1 = (c1 < D1);
    float hd0 = h1[(size_t)n * D1 + c0];
    float hd1 = ok1 ? h1[(size_t)n * D1 + c1] : 0.f;
    float adv = Z[(size_t)n * ZW + 132 + h] + cc[h];
    int E0 = roff[n], E1 = roff[n + 1];
    int hd2 = (E1 - E0 + 1) >> 1;
    int e  = E0 + (half ? hd2 : 0);
    int e1 = half ? E1 : (E0 + hd2);
    float m = -INFINITY, lsum = 0.f, a0 = 0.f, a1 = 0.f;
    const float isc = 0.04264014327112209f;  // 1/sqrt(550)
    int hD = h * D1;
    for (; e + 3 < e1; e += 4) {
        int s0 = elist[e], s1 = elist[e + 1], s2 = elist[e + 2], s3 = elist[e + 3];
        const float* z0 = Z + (size_t)s0 * ZW;
        const float* z1 = Z + (size_t)s1 * ZW;
        const float* z2 = Z + (size_t)s2 * ZW;
        const float* z3 = Z + (size_t)s3 * ZW;
        float p0 = hd0 * z0[hD + c0] + (ok1 ? hd1 * z0[hD + c1] : 0.f);
        float p1 = hd0 * z1[hD + c0] + (ok1 ? hd1 * z1[hD + c1] : 0.f);
        float p2 = hd0 * z2[hD + c0] + (ok1 ? hd1 * z2[hD + c1] : 0.f);
        float p3 = hd0 * z3[hD + c0] + (ok1 ? hd1 * z3[hD + c1] : 0.f);
        #pragma unroll
        for (int off = 32; off >= 1; off >>= 1) {
            p0 += __shfl_xor(p0, off, 64);
            p1 += __shfl_xor(p1, off, 64);
            p2 += __shfl_xor(p2, off, 64);
            p3 += __shfl_xor(p3, off, 64);
        }
        float al0 = (p0 + adv + z0[134 + h]) * isc;
        float al1 = (p1 + adv + z1[134 + h]) * isc;
        float al2 = (p2 + adv + z2[134 + h]) * isc;
        float al3 = (p3 + adv + z3[134 + h]) * isc;
        float va00 = h1[(size_t)s0 * D1 + c0];
        float va01 = ok1 ? h1[(size_t)s0 * D1 + c1] : 0.f;
        float va10 = h1[(size_t)s1 * D1 + c0];
        float va11 = ok1 ? h1[(size_t)s1 * D1 + c1] : 0.f;
        float va20 = h1[(size_t)s2 * D1 + c0];
        float va21 = ok1 ? h1[(size_t)s2 * D1 + c1] : 0.f;
        float va30 = h1[(size_t)s3 * D1 + c0];
        float va31 = ok1 ? h1[(size_t)s3 * D1 + c1] : 0.f;
        float mp = fmaxf(fmaxf(al0, al1), fmaxf(al2, al3));
        float e0v = __expf(al0 - mp), e1v = __expf(al1 - mp);
        float e2v = __expf(al2 - mp), e3v = __expf(al3 - mp);
        float lp = (e0v + e1v) + (e2v + e3v);
        float ap0 = (e0v * va00 + e1v * va10) + (e2v * va20 + e3v * va30);
        float ap1 = (e0v * va01 + e1v * va11) + (e2v * va21 + e3v * va31);
        float mnew = fmaxf(m, mp);
        float sc = __expf(m - mnew), sp = __expf(mp - mnew);
        lsum = lsum * sc + lp * sp;
        a0 = a0 * sc + ap0 * sp;
        a1 = a1 * sc + ap1 * sp;
        m = mnew;
    }
    for (; e + 1 < e1; e += 2) {
        int sa = elist[e], sb = elist[e + 1];
        const float* za = Z + (size_t)sa * ZW;
        const float* zb = Z + (size_t)sb * ZW;
        float pa = hd0 * za[hD + c0] + (ok1 ? hd1 * za[hD + c1] : 0.f);
        float pb = hd0 * zb[hD + c0] + (ok1 ? hd1 * zb[hD + c1] : 0.f);
        #pragma unroll
        for (int off = 32; off >= 1; off >>= 1) {
            pa += __shfl_xor(pa, off, 64);
            pb += __shfl_xor(pb, off, 64);
        }
        float aa = (pa + adv + za[134 + h]) * isc;
        float ab = (pb + adv + zb[134 + h]) * isc;
        float va0 = h1[(size_t)sa * D1 + c0];
        float va1 = ok1 ? h1[(size_t)sa * D1 + c1] : 0.f;
        float vb0 = h1[(size_t)sb * D1 + c0];
        float vb1 = ok1 ? h1[(size_t)sb * D1 + c1] : 0.f;
        float mp = fmaxf(aa, ab);
        float ea = __expf(aa - mp), eb = __expf(ab - mp);
        float lp = ea + eb;
        float ap0 = ea * va0 + eb * vb0;
        float ap1 = ea * va1 + eb * vb1;
        float mnew = fmaxf(m, mp);
        float sc = __expf(m - mnew), sp = __expf(mp - mnew);
        lsum = lsum * sc + lp * sp;
        a0 = a0 * sc + ap0 * sp;
        a1 = a1 * sc + ap1 * sp;
        m = mnew;
    }
    if (e < e1) {
        int s = elist[e];
        const float* zr = Z + (size_t)s * ZW;
        float prod = hd0 * zr[hD + c0] + (ok1 ? hd1 * zr[hD + c1] : 0.f);
        #pragma unroll
        for (int off = 32; off >= 1; off >>= 1) prod += __shfl_xor(prod, off, 64);
        float alpha = (prod + adv + zr[134 + h]) * isc;
        float mnew = fmaxf(m, alpha);
        float sc = __expf(m - mnew);
        float p = __expf(alpha - mnew);
        lsum = lsum * sc + p;
        float v0 = h1[(size_t)s * D1 + c0];
        float vv1 = ok1 ? h1[(size_t)s * D1 + c1] : 0.f;
        a0 = a0 * sc + p * v0;
        a1 = a1 * sc + p * vv1;
        m = mnew;
    }
    if (half) {
        sm_m[wid] = m; sm_l[wid] = lsum;
        sm_a0[h][lane] = a0;
        if (lane < 2) sm_a1[h][lane] = a1;
    }
    __syncthreads();
    if (!half) {
        float mB = sm_m[wid + 1], lB = sm_l[wid + 1];
        float a0B = sm_a0[h][lane];
        float a1B = (lane < 2) ? sm_a1[h][lane] : 0.f;
        float mnew = fmaxf(m, mB);
        float sA = (m > -INFINITY) ? __expf(m - mnew) : 0.f;
        float sB = (mB > -INFINITY) ? __expf(mB - mnew) : 0.f;
        lsum = lsum * sA + lB * sB;
        a0 = a0 * sA + a0B * sB;
        a1 = a1 * sA + a1B * sB;
        float inv = (lsum > 0.f) ? 1.f / lsum : 0.f;
        size_t ub = (size_t)n * KU;
        U[ub + hD + c0] = f2bf(a0 * inv);
        if (ok1) U[ub + hD + c1] = f2bf(a1 * inv);
        // flag col (bf16 1.0 = 0x3F80): U[198+h]
        if (lane == 0) U[ub + 198 + h] = (lsum > 0.f) ? (unsigned short)0x3F80 : (unsigned short)0;
        if (h == 0) {
            // h1 bf16 copy into U[132..197]
            U[ub + 132 + c0] = f2bf(hd0);
            if (ok1) U[ub + 132 + c1] = f2bf(hd1);
            if (lane == 1) U[ub + 223] = (unsigned short)0x3F80;   // const-1 col (bias)
        } else if (lane >= 34 && lane < 57) {
            U[ub + 200 + (lane - 34)] = 0;                          // zero pad 200..222
        }
    }
}

// ---------------- MFMA GEMM 2: out = pairmax(U @ W2t^T); bias/flag folded into K ----------------
__global__ __launch_bounds__(256) void k_mm2(
        const unsigned short* __restrict__ A, const unsigned short* __restrict__ B,
        float* __restrict__ out, int N, int nRow, int slots) {
    __shared__ float ot[4][32][49];
    int s = xcd_slot(blockIdx.x, slots);
    if (s >= nRow * 12) return;
    int rowt = s / 12, g = s - rowt * 12;
    int wave = threadIdx.x >> 6, lane = threadIdx.x & 63;
    int lr = lane & 15, lk = lane >> 4;
    int rbase = rowt * 128 + wave * 32;
    int ar[2];
    #pragma unroll
    for (int mi = 0; mi < 2; mi++) {
        int r = rbase + mi * 16 + lr;
        ar[mi] = (r < N) ? r : (N - 1);
    }
    bfrag a[2][7];
    #pragma unroll
    for (int mi = 0; mi < 2; mi++)
        #pragma unroll
        for (int ks = 0; ks < 7; ks++)
            a[mi][ks] = *(const bfrag*)(A + (size_t)ar[mi] * KU + ks * 32 + lk * 8);
    f32x4 acc[2][6];
    #pragma unroll
    for (int mi = 0; mi < 2; mi++)
        #pragma unroll
        for (int ni = 0; ni < 6; ni++) acc[mi][ni] = (f32x4){0.f, 0.f, 0.f, 0.f};
    #pragma unroll
    for (int ks = 0; ks < 7; ks++) {
        bfrag b[6];
        #pragma unroll
        for (int ni = 0; ni < 6; ni++)
            b[ni] = *(const bfrag*)(B + (size_t)(g * 7 + ks) * 3072 + lk * 768 + (ni * 16 + lr) * 8);
        #pragma unroll
        for (int mi = 0; mi < 2; mi++)
            #pragma unroll
            for (int ni = 0; ni < 6; ni++)
                acc[mi][ni] = __builtin_amdgcn_mfma_f32_16x16x32_bf16(a[mi][ks], b[ni], acc[mi][ni], 0, 0, 0);
    }
    // pair-max into per-wave LDS tile
    #pragma unroll
    for (int mi = 0; mi < 2; mi++) {
        #pragma unroll
        for (int ni = 0; ni < 6; ni++) {
            #pragma unroll
            for (int r = 0; r < 4; r++) {
                float val = acc[mi][ni][r];
                float oth = __shfl_xor(val, 1, 64);
                if (!(lane & 1))
                    ot[wave][mi * 16 + lk * 4 + r][ni * 8 + (lr >> 1)] = fmaxf(val, oth);
            }
        }
    }
    __syncthreads();
    // coalesced write: 32 rows x 48 cols per wave
    int colb = g * 48;
    #pragma unroll
    for (int i = 0; i < 24; i++) {
        int t = i * 64 + lane;
        int r32 = t / 48, pos = t - r32 * 48;
        int row = rbase + r32;
        int col = colb + pos;
        if (row < N && col < C2)
            out[(size_t)row * C2 + col] = ot[wave][r32][pos];
    }
}

// ---------------- launcher ----------------
extern "C" void kernel_launch(void* const* d_in, const int* in_sizes, int n_in,
                              void* d_out, int out_size, void* d_ws, size_t ws_size,
                              hipStream_t stream) {
    const float* x  = (const float*)d_in[0];
    const int*   ei = (const int*)d_in[1];
    int N = in_sizes[0] / IN1;
    int E = in_sizes[1] / 2;
    const int* src = ei;
    const int* dst = ei + E;

    const float *Wq1 = (const float*)d_in[2],  *bq1 = (const float*)d_in[3];
    const float *Wk1 = (const float*)d_in[4],  *bk1 = (const float*)d_in[5];
    const float *Wv1 = (const float*)d_in[6],  *bv1 = (const float*)d_in[7];
    const float *Ws1 = (const float*)d_in[8],  *bs1 = (const float*)d_in[9];
    const float *Wq2 = (const float*)d_in[10], *bq2 = (const float*)d_in[11];
    const float *Wk2 = (const float*)d_in[12], *bk2 = (const float*)d_in[13];
    const float *Wv2 = (const float*)d_in[14], *bv2 = (const float*)d_in[15];
    const float *Ws2 = (const float*)d_in[16], *bs2 = (const float*)d_in[17];

    char* w = (char*)d_ws;
    size_t off = 0;
    auto take = [&](size_t bytes) { size_t o = off; off = (off + bytes + 255) & ~(size_t)255; return o; };

    unsigned short* xb = (unsigned short*)(w + take((size_t)N * IN1 * 2));
    size_t proj_off = take((size_t)N * PROJW * 4);
    float* proj = (float*)(w + proj_off);
    // aliased into proj region AFTER conv1 consumes proj:
    float* Z = proj;                                                       // N*144*4 = 11.52 MB
    unsigned short* U = (unsigned short*)(w + proj_off + (size_t)N * ZW * 4);  // N*224*2 = 8.96 MB
    float* h1   = (float*)(w + take((size_t)N * D1 * 4));
    unsigned short* h1b = (unsigned short*)(w + take((size_t)N * KZ * 2));
    float* G    = (float*)(w + take((size_t)2 * D1 * D1 * 4));
    float* wqbk = (float*)(w + take(2 * D1 * 4));
    float* wkbq = (float*)(w + take(2 * D1 * 4));
    float* cc   = (float*)(w + take(2 * 4));
    unsigned short* GBt = (unsigned short*)(w + take((size_t)24 * 96 * 8 * 2));
    unsigned short* Wt1 = (unsigned short*)(w + take((size_t)96 * 96 * 8 * 2));
    float* bcat = (float*)(w + take(PROJW * 4));
    unsigned short* W2t = (unsigned short*)(w + take((size_t)336 * 96 * 8 * 2));
    int* cnt   = (int*)(w + take((size_t)N * 4));
    int* roff  = (int*)(w + take((size_t)(N + 1) * 4));
    int* pos   = (int*)(w + take((size_t)N * 4));
    int* elist = (int*)(w + take((size_t)E * 4));

    // CSR by dst
    hipMemsetAsync(cnt, 0, (size_t)N * sizeof(int), stream);
    k_hist<<<(E + 255) / 256, 256, 0, stream>>>(dst, E, cnt);
    k_scan<<<1, 1024, 0, stream>>>(cnt, roff, pos, N);
    k_fill<<<(E + 255) / 256, 256, 0, stream>>>(src, dst, E, pos, elist);

    // conversions + weight prep (fragment-order layouts)
    k_cvt<<<(N * IN1 / 4 + 255) / 256, 256, 0, stream>>>(x, xb, N * IN1 / 4);
    k_prep1<<<96, 96, 0, stream>>>(Wq1, bq1, Wk1, bk1, Wv1, bv1, Ws1, bs1, Wt1, bcat);
    k_prep2<<<336, 96, 0, stream>>>(Wv2, bv2, Ws2, bs2, W2t);
    k_precomp<<<(8978 + 3) / 4, 256, 0, stream>>>(Wq2, bq2, Wk2, bk2, G, wqbk, wkbq, cc);
    k_prepz<<<24, 96, 0, stream>>>(G, wqbk, wkbq, GBt);

    // grid sizes with XCD swizzle padding
    int nRow1 = (N + 127) / 128;
    int tot1  = nRow1 * 3;
    int slots1 = (tot1 + 7) / 8;
    int nRowZ = (N + 63) / 64;
    int totZ  = nRowZ * 2;
    int slotsZ = (totZ + 7) / 8;
    int nRow2 = (N + 127) / 128;
    int tot2  = nRow2 * 12;
    int slots2 = (tot2 + 7) / 8;

    // conv1: projections (MFMA) + edge phase (4-wave split)
    k_mm1<<<slots1 * 8, 256, 0, stream>>>(xb, Wt1, bcat, proj, N, nRow1, slots1);
    k_conv1<<<N, 256, 0, stream>>>(proj, roff, elist, h1, h1b, N);

    // z-GEMM (MFMA)
    k_mmz<<<slotsZ * 8, 256, 0, stream>>>(h1b, GBt, Z, N, nRowZ, slotsZ);

    // conv2 edge phase (4-wave split; writes U: agg + h1 copy + flag/one columns)
    k_conv2<<<N, 256, 0, stream>>>(h1, Z, cc, roff, elist, U, N);

    // final fused GEMM (bias/flag folded into K) + pair-max epilogue
    k_mm2<<<slots2 * 8, 256, 0, stream>>>(U, W2t, (float*)d_out, N, nRow2, slots2);
}

// Round 11
// 173.088 us; speedup vs baseline: 1.1195x; 1.1195x over previous
//
#include <hip/hip_runtime.h>
#include <math.h>

#define HEADS 2
#define C1    33
#define C2    550
#define D1    66     // HEADS*C1
#define D2    1100   // HEADS*C2
#define IN1   256
#define PROJW 288    // padded q|k|v|s width (264 -> 288 = 3*96)
#define KU    224    // padded U width (198 -> 224 = 7*32)
#define N2P   1152   // padded final cols (1100 -> 1152 = 12*96)
#define KZ    96     // padded K for z-GEMM (66 -> 96)
#define ZW    144    // Z row stride (136 used -> 144)

typedef __attribute__((ext_vector_type(8))) short bfrag;   // 8 bf16 (bits in short)
typedef __attribute__((ext_vector_type(4))) float f32x4;

__device__ inline unsigned short f2bf(float f) {
    unsigned int u = __float_as_uint(f);
    u += 0x7FFFu + ((u >> 16) & 1u);
    return (unsigned short)(u >> 16);
}

// XCD-aware swizzle: blocks with equal bid%8 (same XCD) get contiguous work
// slots, so all col-groups of a row-tile run on one XCD and share its L2.
__device__ inline int xcd_slot(int bid, int slots) {
    return (bid >> 3) + (bid & 7) * slots;
}

// ---------------- fp32 -> bf16 conversion of x ----------------
__global__ void k_cvt(const float* __restrict__ x, unsigned short* __restrict__ xb, int total4) {
    int i = blockIdx.x * blockDim.x + threadIdx.x;
    if (i >= total4) return;
    float4 v = ((const float4*)x)[i];
    ushort4 o;
    o.x = f2bf(v.x); o.y = f2bf(v.y); o.z = f2bf(v.z); o.w = f2bf(v.w);
    ((ushort4*)xb)[i] = o;
}

// ---------------- Wt1 fragment-order [3][8][4][96][8] + bcat[288] ----------------
__global__ void k_prep1(const float* __restrict__ Wq, const float* __restrict__ bq,
                        const float* __restrict__ Wk, const float* __restrict__ bk,
                        const float* __restrict__ Wv, const float* __restrict__ bv,
                        const float* __restrict__ Ws, const float* __restrict__ bs,
                        unsigned short* __restrict__ Wt1, float* __restrict__ bcat) {
    int bid = blockIdx.x;            // (g*8+ks)*4+lk, 96 blocks
    int lk = bid & 3, t = bid >> 2;
    int ks = t & 7, g = t >> 3;
    int col = threadIdx.x;           // 0..95
    int c = g * 96 + col;
    int k0 = ks * 32 + lk * 8;
    short vals[8];
    float bia = 0.f;
    if (c < 4 * D1) {
        int m = c / D1, j = c % D1;
        const float* W; const float* B;
        switch (m) {
            case 0: W = Wq; B = bq; break;
            case 1: W = Wk; B = bk; break;
            case 2: W = Wv; B = bv; break;
            default: W = Ws; B = bs; break;
        }
        #pragma unroll
        for (int e = 0; e < 8; e++) vals[e] = (short)f2bf(W[(size_t)(k0 + e) * D1 + j]);
        bia = B[j];
    } else {
        #pragma unroll
        for (int e = 0; e < 8; e++) vals[e] = 0;
    }
    *(bfrag*)&Wt1[((size_t)bid * 96 + col) * 8] = *(bfrag*)vals;
    if (ks == 0 && lk == 0) bcat[c] = bia;
}

// ---------------- W2t fragment-order [12][7][4][96][8] ----------------
// rows 198/199 = head-masked bv2 (flag columns); row 223 = bs2 (const-1 column).
__global__ void k_prep2(const float* __restrict__ Wv2, const float* __restrict__ bv2,
                        const float* __restrict__ Ws2, const float* __restrict__ bs2,
                        unsigned short* __restrict__ W2t) {
    int bid = blockIdx.x;            // (g*7+ks)*4+lk, 336 blocks
    int lk = bid & 3, t = bid >> 2;
    int ks = t % 7, g = t / 7;
    int col = threadIdx.x;           // 0..95
    int c = g * 96 + col;
    int k0 = ks * 32 + lk * 8;
    short vals[8];
    #pragma unroll
    for (int e = 0; e < 8; e++) {
        int k = k0 + e;
        float val = 0.f;
        if (c < D2) {
            if (c < C2) {
                if (k < 66) val = Wv2[(size_t)k * D2 + c];
                else if (k >= 132 && k < 198) val = Ws2[(size_t)(k - 132) * D2 + c];
                else if (k == 198) val = bv2[c];
                else if (k == 223) val = bs2[c];
            } else {
                if (k >= 66 && k < 132) val = Wv2[(size_t)(k - 66) * D2 + c];
                else if (k >= 132 && k < 198) val = Ws2[(size_t)(k - 132) * D2 + c];
                else if (k == 199) val = bv2[c];
                else if (k == 223) val = bs2[c];
            }
        }
        vals[e] = (short)f2bf(val);
    }
    *(bfrag*)&W2t[((size_t)bid * 96 + col) * 8] = *(bfrag*)vals;
}

// ---------------- CSR construction ----------------
__global__ void k_hist(const int* __restrict__ dst, int E, int* __restrict__ cnt) {
    int e = blockIdx.x * blockDim.x + threadIdx.x;
    if (e < E) atomicAdd(&cnt[dst[e]], 1);
}

__global__ void k_scan(const int* __restrict__ cnt, int* __restrict__ roff,
                       int* __restrict__ pos, int N) {
    __shared__ int wsum[16];
    __shared__ int carry_s;
    int tid = threadIdx.x, wid = tid >> 6, lane = tid & 63;
    if (tid == 0) { carry_s = 0; roff[0] = 0; }
    __syncthreads();
    for (int base = 0; base < N; base += 1024) {
        int i = base + tid;
        int v = (i < N) ? cnt[i] : 0;
        int x = v;
        #pragma unroll
        for (int s = 1; s < 64; s <<= 1) {
            int t = __shfl_up(x, s, 64);
            if (lane >= s) x += t;
        }
        if (lane == 63) wsum[wid] = x;
        __syncthreads();
        if (tid < 16) {
            int y = wsum[tid];
            #pragma unroll
            for (int s = 1; s < 16; s <<= 1) {
                int t = __shfl_up(y, s, 16);
                if (tid >= s) y += t;
            }
            wsum[tid] = y;
        }
        __syncthreads();
        int carry = carry_s;
        int incl = carry + (wid ? wsum[wid - 1] : 0) + x;
        if (i < N) { roff[i + 1] = incl; pos[i] = incl - v; }
        __syncthreads();
        if (tid == 0) carry_s = carry + wsum[15];
        __syncthreads();
    }
}

__global__ void k_fill(const int* __restrict__ src, const int* __restrict__ dst, int E,
                       int* __restrict__ pos, int* __restrict__ elist) {
    int e = blockIdx.x * blockDim.x + threadIdx.x;
    if (e < E) {
        int slot = atomicAdd(&pos[dst[e]], 1);
        elist[slot] = src[e];
    }
}

// ---------------- MFMA GEMM 1: proj[N][288] = x_bf16 @ W^T + bcat ----------------
__global__ __launch_bounds__(256) void k_mm1(
        const unsigned short* __restrict__ A, const unsigned short* __restrict__ B,
        const float* __restrict__ bias, float* __restrict__ proj, int N,
        int nRow, int slots) {
    int s = xcd_slot(blockIdx.x, slots);
    if (s >= nRow * 3) return;
    int rowt = s / 3, g = s - rowt * 3;
    int cbase = g * 96;
    int wave = threadIdx.x >> 6, lane = threadIdx.x & 63;
    int lr = lane & 15, lk = lane >> 4;
    int rbase = rowt * 128 + wave * 32;
    int ar[2];
    #pragma unroll
    for (int mi = 0; mi < 2; mi++) {
        int r = rbase + mi * 16 + lr;
        ar[mi] = (r < N) ? r : (N - 1);
    }
    bfrag a[2][8];
    #pragma unroll
    for (int mi = 0; mi < 2; mi++)
        #pragma unroll
        for (int ks = 0; ks < 8; ks++)
            a[mi][ks] = *(const bfrag*)(A + (size_t)ar[mi] * IN1 + ks * 32 + lk * 8);
    f32x4 acc[2][6];
    #pragma unroll
    for (int mi = 0; mi < 2; mi++)
        #pragma unroll
        for (int ni = 0; ni < 6; ni++) acc[mi][ni] = (f32x4){0.f, 0.f, 0.f, 0.f};
    #pragma unroll
    for (int ks = 0; ks < 8; ks++) {
        bfrag b[6];
        #pragma unroll
        for (int ni = 0; ni < 6; ni++)
            b[ni] = *(const bfrag*)(B + (size_t)(g * 8 + ks) * 3072 + lk * 768 + (ni * 16 + lr) * 8);
        #pragma unroll
        for (int mi = 0; mi < 2; mi++)
            #pragma unroll
            for (int ni = 0; ni < 6; ni++)
                acc[mi][ni] = __builtin_amdgcn_mfma_f32_16x16x32_bf16(a[mi][ks], b[ni], acc[mi][ni], 0, 0, 0);
    }
    #pragma unroll
    for (int mi = 0; mi < 2; mi++) {
        #pragma unroll
        for (int ni = 0; ni < 6; ni++) {
            int col = cbase + ni * 16 + lr;
            float bia = bias[col];
            #pragma unroll
            for (int r = 0; r < 4; r++) {
                int row = rbase + mi * 16 + lk * 4 + r;
                if (row < N) proj[(size_t)row * PROJW + col] = acc[mi][ni][r] + bia;
            }
        }
    }
}

// ---------------- conv1: wave=head, half-wave per edge (dims via l32) ----------------
__global__ __launch_bounds__(128) void k_conv1(
        const float* __restrict__ proj, const int* __restrict__ roff,
        const int* __restrict__ elist, float* __restrict__ h1,
        unsigned short* __restrict__ h1b, int N) {
    int n = blockIdx.x;
    int h = threadIdx.x >> 6;
    int lane = threadIdx.x & 63;
    int half = lane >> 5, l32 = lane & 31;
    size_t pb = (size_t)n * PROJW;
    int hc = h * C1;
    float q_a = proj[pb + hc + l32];                      // dims 0..31
    float q_b = (l32 == 0) ? proj[pb + hc + 32] : 0.f;    // dim 32
    int E0 = roff[n], E1 = roff[n + 1];
    float m = -INFINITY, lsum = 0.f, aca = 0.f, acb = 0.f;
    const float isc = 0.17407765595569785f;  // 1/sqrt(33)
    int i = E0 + half;
    for (; i + 2 < E1; i += 4) {
        int s0 = elist[i], s1 = elist[i + 2];
        size_t b0 = (size_t)s0 * PROJW, b1 = (size_t)s1 * PROJW;
        float k0a = proj[b0 + 66 + hc + l32];
        float k0b = (l32 == 0) ? proj[b0 + 66 + hc + 32] : 0.f;
        float k1a = proj[b1 + 66 + hc + l32];
        float k1b = (l32 == 0) ? proj[b1 + 66 + hc + 32] : 0.f;
        float v0a = proj[b0 + 132 + hc + l32];
        float v0b = (l32 == 0) ? proj[b0 + 132 + hc + 32] : 0.f;
        float v1a = proj[b1 + 132 + hc + l32];
        float v1b = (l32 == 0) ? proj[b1 + 132 + hc + 32] : 0.f;
        float p0 = q_a * k0a + q_b * k0b;
        float p1 = q_a * k1a + q_b * k1b;
        #pragma unroll
        for (int off = 16; off >= 1; off >>= 1) {
            p0 += __shfl_xor(p0, off, 32);
            p1 += __shfl_xor(p1, off, 32);
        }
        float a0 = p0 * isc, a1 = p1 * isc;
        float mp = fmaxf(a0, a1);
        float e0 = __expf(a0 - mp), e1 = __expf(a1 - mp);
        float lp = e0 + e1;
        float apa = e0 * v0a + e1 * v1a;
        float apb = e0 * v0b + e1 * v1b;
        float mnew = fmaxf(m, mp);
        float sc = __expf(m - mnew), sp = __expf(mp - mnew);
        lsum = lsum * sc + lp * sp;
        aca = aca * sc + apa * sp;
        acb = acb * sc + apb * sp;
        m = mnew;
    }
    for (; i < E1; i += 2) {
        int s = elist[i];
        size_t sb = (size_t)s * PROJW;
        float ka = proj[sb + 66 + hc + l32];
        float kb = (l32 == 0) ? proj[sb + 66 + hc + 32] : 0.f;
        float va = proj[sb + 132 + hc + l32];
        float vb = (l32 == 0) ? proj[sb + 132 + hc + 32] : 0.f;
        float p = q_a * ka + q_b * kb;
        #pragma unroll
        for (int off = 16; off >= 1; off >>= 1) p += __shfl_xor(p, off, 32);
        float alpha = p * isc;
        float mnew = fmaxf(m, alpha);
        float sc = __expf(m - mnew);
        float pe = __expf(alpha - mnew);
        lsum = lsum * sc + pe;
        aca = aca * sc + pe * va;
        acb = acb * sc + pe * vb;
        m = mnew;
    }
    // merge the two halves (register shuffles across lane^32; -inf safe)
    float mO  = __shfl_xor(m, 32, 64);
    float lO  = __shfl_xor(lsum, 32, 64);
    float aaO = __shfl_xor(aca, 32, 64);
    float abO = __shfl_xor(acb, 32, 64);
    float mnew = fmaxf(m, mO);
    float sS = (m  > -INFINITY) ? __expf(m  - mnew) : 0.f;
    float sO = (mO > -INFINITY) ? __expf(mO - mnew) : 0.f;
    lsum = lsum * sS + lO * sO;
    aca  = aca * sS + aaO * sO;
    acb  = acb * sS + abO * sO;
    float inv = (lsum > 0.f) ? 1.f / lsum : 0.f;
    if (half == 0) {
        float s1a = proj[pb + 198 + hc + l32];
        float val = aca * inv + s1a;
        h1[(size_t)n * D1 + hc + l32] = val;
        h1b[(size_t)n * KZ + hc + l32] = f2bf(val);
        if (l32 == 0) {
            float s1b = proj[pb + 198 + hc + 32];
            float valb = acb * inv + s1b;
            h1[(size_t)n * D1 + hc + 32] = valb;
            h1b[(size_t)n * KZ + hc + 32] = f2bf(valb);
        }
    } else if (h == 1 && l32 < 30) {
        h1b[(size_t)n * KZ + D1 + l32] = 0;   // zero pad cols 66..95
    }
}

// ---------------- precompute G = Wq2_h Wk2_h^T + bias dots: one wave per dot ----------------
__global__ __launch_bounds__(256) void k_precomp(
        const float* __restrict__ Wq2, const float* __restrict__ bq2,
        const float* __restrict__ Wk2, const float* __restrict__ bk2,
        float* __restrict__ G, float* __restrict__ wqbk,
        float* __restrict__ wkbq, float* __restrict__ cc) {
    int wave = threadIdx.x >> 6, lane = threadIdx.x & 63;
    int j = blockIdx.x * 4 + wave;
    if (j >= 8978) return;
    const float *u, *v;
    float* outp;
    if (j < 8976) {
        int h = j / 4488;
        int r = j % 4488;
        int a = r / 68, b = r % 68;
        if (b < 66)      { u = Wq2 + (size_t)a * D2 + h * C2; v = Wk2 + (size_t)b * D2 + h * C2; outp = &G[h * 4356 + a * 66 + b]; }
        else if (b == 66){ u = Wq2 + (size_t)a * D2 + h * C2; v = bk2 + h * C2;                  outp = &wqbk[h * 66 + a]; }
        else             { u = Wk2 + (size_t)a * D2 + h * C2; v = bq2 + h * C2;                  outp = &wkbq[h * 66 + a]; }
    } else {
        int h = j - 8976;
        u = bq2 + h * C2; v = bk2 + h * C2; outp = &cc[h];
    }
    float acc = 0.f;
    for (int c = lane; c < C2; c += 64) acc += u[c] * v[c];
    #pragma unroll
    for (int off = 32; off >= 1; off >>= 1) acc += __shfl_xor(acc, off, 64);
    if (lane == 0) *outp = acc;
}

// ---------------- GBt fragment-order [2][3][4][96][8] ----------------
__global__ void k_prepz(const float* __restrict__ G, const float* __restrict__ wqbk,
                        const float* __restrict__ wkbq, unsigned short* __restrict__ GBt) {
    int bid = blockIdx.x;            // (g*3+ks)*4+lk, 24 blocks
    int lk = bid & 3, t = bid >> 2;
    int ks = t % 3, g = t / 3;
    int col = threadIdx.x;           // 0..95
    int r = g * 96 + col;
    int k0 = ks * 32 + lk * 8;
    short vals[8];
    #pragma unroll
    for (int e = 0; e < 8; e++) {
        int k = k0 + e;
        float v = 0.f;
        if (k < D1) {
            if (r < 132) v = G[r * D1 + k];
            else if (r < 134) v = wqbk[(r - 132) * D1 + k];
            else if (r < 136) v = wkbq[(r - 134) * D1 + k];
        }
        vals[e] = (short)f2bf(v);
    }
    *(bfrag*)&GBt[((size_t)bid * 96 + col) * 8] = *(bfrag*)vals;
}

// ---------------- MFMA GEMM z: Z[N][144] = h1b[N][96] @ GBt^T (cols 0..135 valid) ----------------
__global__ __launch_bounds__(256) void k_mmz(
        const unsigned short* __restrict__ A, const unsigned short* __restrict__ B,
        float* __restrict__ Z, int N, int nRow, int slots) {
    int s = xcd_slot(blockIdx.x, slots);
    if (s >= nRow * 2) return;
    int rowt = s >> 1, g = s & 1;
    int wave = threadIdx.x >> 6, lane = threadIdx.x & 63;
    int lr = lane & 15, lk = lane >> 4;
    int rbase = rowt * 64 + (wave >> 1) * 32;
    int ch = (wave & 1) * 48;
    int cbase = g * 96 + ch;
    f32x4 acc[2][3];
    #pragma unroll
    for (int i = 0; i < 2; i++)
        #pragma unroll
        for (int j = 0; j < 3; j++) acc[i][j] = (f32x4){0.f, 0.f, 0.f, 0.f};
    int ar[2];
    #pragma unroll
    for (int mi = 0; mi < 2; mi++) {
        int r = rbase + mi * 16 + lr;
        ar[mi] = (r < N) ? r : (N - 1);
    }
    #pragma unroll
    for (int ks = 0; ks < 3; ks++) {
        bfrag a[2], b[3];
        #pragma unroll
        for (int mi = 0; mi < 2; mi++)
            a[mi] = *(const bfrag*)(A + (size_t)ar[mi] * KZ + ks * 32 + lk * 8);
        #pragma unroll
        for (int ni = 0; ni < 3; ni++)
            b[ni] = *(const bfrag*)(B + (size_t)(g * 3 + ks) * 3072 + lk * 768 + (ch + ni * 16 + lr) * 8);
        #pragma unroll
        for (int mi = 0; mi < 2; mi++)
            #pragma unroll
            for (int ni = 0; ni < 3; ni++)
                acc[mi][ni] = __builtin_amdgcn_mfma_f32_16x16x32_bf16(a[mi], b[ni], acc[mi][ni], 0, 0, 0);
    }
    #pragma unroll
    for (int mi = 0; mi < 2; mi++) {
        #pragma unroll
        for (int ni = 0; ni < 3; ni++) {
            int col = cbase + ni * 16 + lr;
            if (col >= 136) continue;
            #pragma unroll
            for (int r = 0; r < 4; r++) {
                int row = rbase + mi * 16 + lk * 4 + r;
                if (row < N) Z[(size_t)row * ZW + col] = acc[mi][ni][r];
            }
        }
    }
}

// ---------------- conv2: wave=head, half-wave per edge (dims via l32) ----------------
__global__ __launch_bounds__(128) void k_conv2(
        const float* __restrict__ h1, const float* __restrict__ Z,
        const float* __restrict__ cc, const int* __restrict__ roff,
        const int* __restrict__ elist, unsigned short* __restrict__ U, int N) {
    int n = blockIdx.x;
    int h = threadIdx.x >> 6;
    int lane = threadIdx.x & 63;
    int half = lane >> 5, l32 = lane & 31;
    int hD = h * D1;
    size_t nb = (size_t)n * D1;
    float hd_a = h1[nb + l32];                       // dims 0..31
    float hd_b = h1[nb + 32 + l32];                  // dims 32..63
    float hd_c = (l32 < 2) ? h1[nb + 64 + l32] : 0.f; // dims 64,65
    float adv = Z[(size_t)n * ZW + 132 + h] + cc[h];
    int E0 = roff[n], E1 = roff[n + 1];
    float m = -INFINITY, lsum = 0.f, aa = 0.f, ab = 0.f, ac = 0.f;
    const float isc = 0.04264014327112209f;  // 1/sqrt(550)
    int i = E0 + half;
    for (; i + 2 < E1; i += 4) {
        int s0 = elist[i], s1 = elist[i + 2];
        const float* z0 = Z + (size_t)s0 * ZW;
        const float* z1 = Z + (size_t)s1 * ZW;
        float z0c = (l32 < 2) ? z0[hD + 64 + l32] : 0.f;
        float z1c = (l32 < 2) ? z1[hD + 64 + l32] : 0.f;
        float p0 = hd_a * z0[hD + l32] + hd_b * z0[hD + 32 + l32] + hd_c * z0c;
        float p1 = hd_a * z1[hD + l32] + hd_b * z1[hD + 32 + l32] + hd_c * z1c;
        float as0 = z0[134 + h], as1 = z1[134 + h];
        #pragma unroll
        for (int off = 16; off >= 1; off >>= 1) {
            p0 += __shfl_xor(p0, off, 32);
            p1 += __shfl_xor(p1, off, 32);
        }
        float al0 = (p0 + adv + as0) * isc;
        float al1 = (p1 + adv + as1) * isc;
        size_t v0b = (size_t)s0 * D1, v1b = (size_t)s1 * D1;
        float v0a = h1[v0b + l32], v0bb = h1[v0b + 32 + l32];
        float v0c = (l32 < 2) ? h1[v0b + 64 + l32] : 0.f;
        float v1a = h1[v1b + l32], v1bb = h1[v1b + 32 + l32];
        float v1c = (l32 < 2) ? h1[v1b + 64 + l32] : 0.f;
        float mp = fmaxf(al0, al1);
        float e0 = __expf(al0 - mp), e1 = __expf(al1 - mp);
        float lp = e0 + e1;
        float mnew = fmaxf(m, mp);
        float sc = __expf(m - mnew), sp = __expf(mp - mnew);
        lsum = lsum * sc + lp * sp;
        aa = aa * sc + (e0 * v0a + e1 * v1a) * sp;
        ab = ab * sc + (e0 * v0bb + e1 * v1bb) * sp;
        ac = ac * sc + (e0 * v0c + e1 * v1c) * sp;
        m = mnew;
    }
    for (; i < E1; i += 2) {
        int s = elist[i];
        const float* zr = Z + (size_t)s * ZW;
        float zc = (l32 < 2) ? zr[hD + 64 + l32] : 0.f;
        float p = hd_a * zr[hD + l32] + hd_b * zr[hD + 32 + l32] + hd_c * zc;
        float as_ = zr[134 + h];
        #pragma unroll
        for (int off = 16; off >= 1; off >>= 1) p += __shfl_xor(p, off, 32);
        float alpha = (p + adv + as_) * isc;
        size_t vb = (size_t)s * D1;
        float va = h1[vb + l32], vbb = h1[vb + 32 + l32];
        float vc = (l32 < 2) ? h1[vb + 64 + l32] : 0.f;
        float mnew = fmaxf(m, alpha);
        float sc = __expf(m - mnew);
        float pe = __expf(alpha - mnew);
        lsum = lsum * sc + pe;
        aa = aa * sc + pe * va;
        ab = ab * sc + pe * vbb;
        ac = ac * sc + pe * vc;
        m = mnew;
    }
    // merge halves (register shuffles across lane^32; -inf safe)
    float mO  = __shfl_xor(m, 32, 64);
    float lO  = __shfl_xor(lsum, 32, 64);
    float aaO = __shfl_xor(aa, 32, 64);
    float abO = __shfl_xor(ab, 32, 64);
    float acO = __shfl_xor(ac, 32, 64);
    float mnew = fmaxf(m, mO);
    float sS = (m  > -INFINITY) ? __expf(m  - mnew) : 0.f;
    float sO = (mO > -INFINITY) ? __expf(mO - mnew) : 0.f;
    lsum = lsum * sS + lO * sO;
    aa = aa * sS + aaO * sO;
    ab = ab * sS + abO * sO;
    ac = ac * sS + acO * sO;
    float inv = (lsum > 0.f) ? 1.f / lsum : 0.f;
    size_t ub = (size_t)n * KU;
    if (half == 0) {
        U[ub + hD + l32] = f2bf(aa * inv);
        if (l32 < 2) U[ub + hD + 64 + l32] = f2bf(ac * inv);
    } else {
        U[ub + hD + 32 + l32] = f2bf(ab * inv);
    }
    if (lane == 0) U[ub + 198 + h] = (lsum > 0.f) ? (unsigned short)0x3F80 : (unsigned short)0;
    if (h == 0) {
        if (half == 0) {
            U[ub + 132 + l32] = f2bf(hd_a);
            if (l32 < 2) U[ub + 132 + 64 + l32] = f2bf(hd_c);
            if (l32 == 2) U[ub + 223] = (unsigned short)0x3F80;   // const-1 col (bias)
        } else {
            U[ub + 132 + 32 + l32] = f2bf(hd_b);
        }
    } else if (half == 1 && l32 < 23) {
        U[ub + 200 + l32] = 0;                                    // zero pad 200..222
    }
}

// ---------------- MFMA GEMM 2: out = pairmax(U @ W2t^T); bias/flag folded into K ----------------
__global__ __launch_bounds__(256) void k_mm2(
        const unsigned short* __restrict__ A, const unsigned short* __restrict__ B,
        float* __restrict__ out, int N, int nRow, int slots) {
    __shared__ float ot[4][32][49];
    int s = xcd_slot(blockIdx.x, slots);
    if (s >= nRow * 12) return;
    int rowt = s / 12, g = s - rowt * 12;
    int wave = threadIdx.x >> 6, lane = threadIdx.x & 63;
    int lr = lane & 15, lk = lane >> 4;
    int rbase = rowt * 128 + wave * 32;
    int ar[2];
    #pragma unroll
    for (int mi = 0; mi < 2; mi++) {
        int r = rbase + mi * 16 + lr;
        ar[mi] = (r < N) ? r : (N - 1);
    }
    bfrag a[2][7];
    #pragma unroll
    for (int mi = 0; mi < 2; mi++)
        #pragma unroll
        for (int ks = 0; ks < 7; ks++)
            a[mi][ks] = *(const bfrag*)(A + (size_t)ar[mi] * KU + ks * 32 + lk * 8);
    f32x4 acc[2][6];
    #pragma unroll
    for (int mi = 0; mi < 2; mi++)
        #pragma unroll
        for (int ni = 0; ni < 6; ni++) acc[mi][ni] = (f32x4){0.f, 0.f, 0.f, 0.f};
    #pragma unroll
    for (int ks = 0; ks < 7; ks++) {
        bfrag b[6];
        #pragma unroll
        for (int ni = 0; ni < 6; ni++)
            b[ni] = *(const bfrag*)(B + (size_t)(g * 7 + ks) * 3072 + lk * 768 + (ni * 16 + lr) * 8);
        #pragma unroll
        for (int mi = 0; mi < 2; mi++)
            #pragma unroll
            for (int ni = 0; ni < 6; ni++)
                acc[mi][ni] = __builtin_amdgcn_mfma_f32_16x16x32_bf16(a[mi][ks], b[ni], acc[mi][ni], 0, 0, 0);
    }
    // pair-max into per-wave LDS tile
    #pragma unroll
    for (int mi = 0; mi < 2; mi++) {
        #pragma unroll
        for (int ni = 0; ni < 6; ni++) {
            #pragma unroll
            for (int r = 0; r < 4; r++) {
                float val = acc[mi][ni][r];
                float oth = __shfl_xor(val, 1, 64);
                if (!(lane & 1))
                    ot[wave][mi * 16 + lk * 4 + r][ni * 8 + (lr >> 1)] = fmaxf(val, oth);
            }
        }
    }
    __syncthreads();
    // coalesced write: 32 rows x 48 cols per wave
    int colb = g * 48;
    #pragma unroll
    for (int i = 0; i < 24; i++) {
        int t = i * 64 + lane;
        int r32 = t / 48, pos = t - r32 * 48;
        int row = rbase + r32;
        int col = colb + pos;
        if (row < N && col < C2)
            out[(size_t)row * C2 + col] = ot[wave][r32][pos];
    }
}

// ---------------- launcher ----------------
extern "C" void kernel_launch(void* const* d_in, const int* in_sizes, int n_in,
                              void* d_out, int out_size, void* d_ws, size_t ws_size,
                              hipStream_t stream) {
    const float* x  = (const float*)d_in[0];
    const int*   ei = (const int*)d_in[1];
    int N = in_sizes[0] / IN1;
    int E = in_sizes[1] / 2;
    const int* src = ei;
    const int* dst = ei + E;

    const float *Wq1 = (const float*)d_in[2],  *bq1 = (const float*)d_in[3];
    const float *Wk1 = (const float*)d_in[4],  *bk1 = (const float*)d_in[5];
    const float *Wv1 = (const float*)d_in[6],  *bv1 = (const float*)d_in[7];
    const float *Ws1 = (const float*)d_in[8],  *bs1 = (const float*)d_in[9];
    const float *Wq2 = (const float*)d_in[10], *bq2 = (const float*)d_in[11];
    const float *Wk2 = (const float*)d_in[12], *bk2 = (const float*)d_in[13];
    const float *Wv2 = (const float*)d_in[14], *bv2 = (const float*)d_in[15];
    const float *Ws2 = (const float*)d_in[16], *bs2 = (const float*)d_in[17];

    char* w = (char*)d_ws;
    size_t off = 0;
    auto take = [&](size_t bytes) { size_t o = off; off = (off + bytes + 255) & ~(size_t)255; return o; };

    unsigned short* xb = (unsigned short*)(w + take((size_t)N * IN1 * 2));
    size_t proj_off = take((size_t)N * PROJW * 4);
    float* proj = (float*)(w + proj_off);
    // aliased into proj region AFTER conv1 consumes proj:
    float* Z = proj;                                                       // N*144*4 = 11.52 MB
    unsigned short* U = (unsigned short*)(w + proj_off + (size_t)N * ZW * 4);  // N*224*2 = 8.96 MB
    float* h1   = (float*)(w + take((size_t)N * D1 * 4));
    unsigned short* h1b = (unsigned short*)(w + take((size_t)N * KZ * 2));
    float* G    = (float*)(w + take((size_t)2 * D1 * D1 * 4));
    float* wqbk = (float*)(w + take(2 * D1 * 4));
    float* wkbq = (float*)(w + take(2 * D1 * 4));
    float* cc   = (float*)(w + take(2 * 4));
    unsigned short* GBt = (unsigned short*)(w + take((size_t)24 * 96 * 8 * 2));
    unsigned short* Wt1 = (unsigned short*)(w + take((size_t)96 * 96 * 8 * 2));
    float* bcat = (float*)(w + take(PROJW * 4));
    unsigned short* W2t = (unsigned short*)(w + take((size_t)336 * 96 * 8 * 2));
    int* cnt   = (int*)(w + take((size_t)N * 4));
    int* roff  = (int*)(w + take((size_t)(N + 1) * 4));
    int* pos   = (int*)(w + take((size_t)N * 4));
    int* elist = (int*)(w + take((size_t)E * 4));

    // CSR by dst
    hipMemsetAsync(cnt, 0, (size_t)N * sizeof(int), stream);
    k_hist<<<(E + 255) / 256, 256, 0, stream>>>(dst, E, cnt);
    k_scan<<<1, 1024, 0, stream>>>(cnt, roff, pos, N);
    k_fill<<<(E + 255) / 256, 256, 0, stream>>>(src, dst, E, pos, elist);

    // conversions + weight prep (fragment-order layouts)
    k_cvt<<<(N * IN1 / 4 + 255) / 256, 256, 0, stream>>>(x, xb, N * IN1 / 4);
    k_prep1<<<96, 96, 0, stream>>>(Wq1, bq1, Wk1, bk1, Wv1, bv1, Ws1, bs1, Wt1, bcat);
    k_prep2<<<336, 96, 0, stream>>>(Wv2, bv2, Ws2, bs2, W2t);
    k_precomp<<<(8978 + 3) / 4, 256, 0, stream>>>(Wq2, bq2, Wk2, bk2, G, wqbk, wkbq, cc);
    k_prepz<<<24, 96, 0, stream>>>(G, wqbk, wkbq, GBt);

    // grid sizes with XCD swizzle padding
    int nRow1 = (N + 127) / 128;
    int tot1  = nRow1 * 3;
    int slots1 = (tot1 + 7) / 8;
    int nRowZ = (N + 63) / 64;
    int totZ  = nRowZ * 2;
    int slotsZ = (totZ + 7) / 8;
    int nRow2 = (N + 127) / 128;
    int tot2  = nRow2 * 12;
    int slots2 = (tot2 + 7) / 8;

    // conv1: projections (MFMA) + edge phase (half-wave per edge)
    k_mm1<<<slots1 * 8, 256, 0, stream>>>(xb, Wt1, bcat, proj, N, nRow1, slots1);
    k_conv1<<<N, 128, 0, stream>>>(proj, roff, elist, h1, h1b, N);

    // z-GEMM (MFMA)
    k_mmz<<<slotsZ * 8, 256, 0, stream>>>(h1b, GBt, Z, N, nRowZ, slotsZ);

    // conv2 edge phase (half-wave per edge; writes U: agg + h1 copy + flag/one columns)
    k_conv2<<<N, 128, 0, stream>>>(h1, Z, cc, roff, elist, U, N);

    // final fused GEMM (bias/flag folded into K) + pair-max epilogue
    k_mm2<<<slots2 * 8, 256, 0, stream>>>(U, W2t, (float*)d_out, N, nRow2, slots2);
}